// Round 14
// baseline (298.513 us; speedup 1.0000x reference)
//
#include <hip/hip_runtime.h>

// MyLeNetMatStochBU, B=1024. fp32-VALU l1 (reg-pipelined) + bf16-MFMA l2 (128^2)
// + l3 (64^2, split-K=2).
//
// Structural facts (from reference construction):
//  - mask3 = single position; mask2 = exactly 9 active positions (3x3 block).
//  - mask1 = union of l2's read windows -> masked l1 positions never read.
//  - l3's im2col of h2 == l2's output re-indexed -> gemm_l2 writes P3 directly.
//  - l1 fp32 VALU (MFMA-l1 2.4x slower, r8). r11: l1 latency-bound on weight
//    loads -> register prefetch pipeline this round.
//
// ws layout (BYTE offsets, 16B-aligned):
//   h1b : bf16 (1024,14,14,200) NHWC @ 0            80,281,600 B
//   W2b : bf16 [512][1856]           @  80,281,600   1,900,544 B
//   P3  : bf16 [1024][3648]          @  82,182,144   7,471,104 B
//   W3b : bf16 [832][3648]           @  89,653,248   6,070,272 B
//   h3a : f32  [1024][800]           @  95,723,520   3,276,800 B
//   h3b : f32  [1024][800]           @  99,000,320   3,276,800 B
//   W1t : f32  [80][256] K-major     @ 102,277,120      81,920 B
// total ~102.4 MB.

#define H1B_OFF 0ULL
#define W2B_OFF 80281600ULL
#define P3_OFF  82182144ULL
#define W3B_OFF 89653248ULL
#define H3A_OFF 95723520ULL
#define H3B_OFF 99000320ULL
#define W1T_OFF 102277120ULL

typedef unsigned short u16;
typedef short bf16x8 __attribute__((ext_vector_type(8)));
typedef float f32x4 __attribute__((ext_vector_type(4)));

__device__ __forceinline__ u16 f2bf(float f) {
    union { float f; unsigned int u; } v; v.f = f;
    unsigned int u = v.u + 0x7FFFu + ((v.u >> 16) & 1u);   // RNE
    return (u16)(u >> 16);
}

// ---------- wprep ----------
__global__ __launch_bounds__(256) void wprep(
    const float* __restrict__ W1, const float* __restrict__ W2, const float* __restrict__ W3,
    float* __restrict__ W1t, u16* __restrict__ W2b, u16* __restrict__ W3b)
{
    int idx = blockIdx.x * 256 + threadIdx.x;
    if (idx < 20480) {                               // W1t [80 kk][256 ocp]
        int kk = idx / 256, oc = idx % 256;
        float v = 0.0f;
        if (oc < 200 && kk < 75) v = W1[oc * 75 + kk];
        W1t[idx] = v;
    } else if (idx < 20480 + 950272) {               // W2b [512][1856], kk=k3*200+c
        int j = idx - 20480;
        int oc = j / 1856, kk = j % 1856;
        float v = 0.0f;
        if (oc < 400 && kk < 1800) {
            int k3 = kk / 200, c = kk % 200;
            v = W2[oc * 1800 + c * 9 + k3];
        }
        W2b[j] = f2bf(v);
    } else if (idx < 20480 + 950272 + 3035136) {     // W3b [832][3648], kk=k3*400+c
        int j = idx - 20480 - 950272;
        int oc = j / 3648, kk = j % 3648;
        float v = 0.0f;
        if (oc < 800 && kk < 3600) {
            int k3 = kk / 400, c = kk % 400;
            v = W3[oc * 3600 + c * 9 + k3];
        }
        W3b[j] = f2bf(v);
    }
}

// ---------- L1: fp32 FMA, 4oc x 8u tile, 32 batches/block, weight reg-prefetch ----------
__global__ __launch_bounds__(256) void l1_kernel(
    const float* __restrict__ x, const float* __restrict__ W1t, const float* __restrict__ b1,
    const int* __restrict__ selh, const int* __restrict__ selw, const float* __restrict__ mask,
    u16* __restrict__ h1b)
{
    const int pos = blockIdx.x;              // 0..195
    const float m = mask[pos];
    if (m == 0.0f) return;
    const int i = pos / 14, j = pos % 14;
    const int b0 = blockIdx.y * 32;
    const int tid = threadIdx.x;
    const int ph = min(i * 2 + selh[pos], 27);
    const int pw = min(j * 2 + selw[pos], 27);

    __shared__ __align__(16) float patch[32 * 80];   // [u][kk], kk=c*25+d pad 80
    for (int e = tid; e < 2560; e += 256) {
        int u = e / 80, kk = e % 80;
        float v = 0.0f;
        if (kk < 75) {
            int c = kk / 25, d = kk % 25;
            v = x[((size_t)(b0 + u) * 3 + c) * 1024 + (ph + d / 5) * 32 + (pw + d % 5)];
        }
        patch[e] = v;
    }
    __syncthreads();

    const int g = tid & 63;                  // oc = g*4 .. g*4+3 (padded weights)
    const int us = tid >> 6;                 // u = us*8 .. us*8+7
    const float4* w4 = reinterpret_cast<const float4*>(W1t);     // [80][64]
    const float4* p4 = reinterpret_cast<const float4*>(patch);   // [32][20]

    float4 acc[8];
#pragma unroll
    for (int uu = 0; uu < 8; ++uu) acc[uu] = make_float4(0.f, 0.f, 0.f, 0.f);

    float4 wc[4];
#pragma unroll
    for (int t = 0; t < 4; ++t) wc[t] = w4[t * 64 + g];

    for (int q = 0; q < 20; ++q) {
        // prefetch q+1 weights while FMAs below consume wc (hides ~200cy latency)
        int qq = min(q + 1, 19);
        float4 wn[4];
#pragma unroll
        for (int t = 0; t < 4; ++t) wn[t] = w4[(qq * 4 + t) * 64 + g];

#pragma unroll
        for (int uu = 0; uu < 8; ++uu) {
            float4 p = p4[(us * 8 + uu) * 20 + q];   // wave-uniform broadcast
            acc[uu].x = fmaf(wc[0].x, p.x, acc[uu].x);
            acc[uu].y = fmaf(wc[0].y, p.x, acc[uu].y);
            acc[uu].z = fmaf(wc[0].z, p.x, acc[uu].z);
            acc[uu].w = fmaf(wc[0].w, p.x, acc[uu].w);
            acc[uu].x = fmaf(wc[1].x, p.y, acc[uu].x);
            acc[uu].y = fmaf(wc[1].y, p.y, acc[uu].y);
            acc[uu].z = fmaf(wc[1].z, p.y, acc[uu].z);
            acc[uu].w = fmaf(wc[1].w, p.y, acc[uu].w);
            acc[uu].x = fmaf(wc[2].x, p.z, acc[uu].x);
            acc[uu].y = fmaf(wc[2].y, p.z, acc[uu].y);
            acc[uu].z = fmaf(wc[2].z, p.z, acc[uu].z);
            acc[uu].w = fmaf(wc[2].w, p.z, acc[uu].w);
            acc[uu].x = fmaf(wc[3].x, p.w, acc[uu].x);
            acc[uu].y = fmaf(wc[3].y, p.w, acc[uu].y);
            acc[uu].z = fmaf(wc[3].z, p.w, acc[uu].z);
            acc[uu].w = fmaf(wc[3].w, p.w, acc[uu].w);
        }
#pragma unroll
        for (int t = 0; t < 4; ++t) wc[t] = wn[t];
    }

    if (g < 50) {                            // oc = g*4..g*4+3 all < 200
        float4 bv = reinterpret_cast<const float4*>(b1)[g];
#pragma unroll
        for (int uu = 0; uu < 8; ++uu) {
            int b = b0 + us * 8 + uu;
            ushort4 o;
            o.x = f2bf(fmaxf((acc[uu].x + bv.x) * m, 0.0f));
            o.y = f2bf(fmaxf((acc[uu].y + bv.y) * m, 0.0f));
            o.z = f2bf(fmaxf((acc[uu].z + bv.z) * m, 0.0f));
            o.w = f2bf(fmaxf((acc[uu].w + bv.w) * m, 0.0f));
            *reinterpret_cast<ushort4*>(&h1b[((size_t)b * 196 + pos) * 200 + g * 4]) = o;
        }
    }
}

// ---------- gemm_l2: 128x128 tile, BK=64, fused im2col A-gather -> P3 ----------
// M=9216 (b*9+pidx), K=1800 pad 1856, N=448 pad 512. 4 waves x (4x4) 16x16 frags.
__global__ __launch_bounds__(256) void gemm_l2(
    const u16* __restrict__ h1b, const u16* __restrict__ B, const float* __restrict__ bias,
    const int* __restrict__ selh2, const int* __restrict__ selw2,
    const int* __restrict__ selh3, const int* __restrict__ selw3,
    u16* __restrict__ P3)
{
    const int KP = 1856, NKT = 29;
    const int m0 = blockIdx.x * 128, n0 = blockIdx.y * 128;
    const int tid = threadIdx.x;
    const int lane = tid & 63, wid = tid >> 6;
    const int wm = wid >> 1, wn = wid & 1;

    __shared__ u16 Asm[128][72];
    __shared__ u16 Bsm[128][72];

    f32x4 acc[4][4];
#pragma unroll
    for (int mi = 0; mi < 4; ++mi)
#pragma unroll
        for (int ni = 0; ni < 4; ++ni) {
            f32x4 z = {0.f, 0.f, 0.f, 0.f};
            acc[mi][ni] = z;
        }

    const int ar = tid >> 3, ac = tid & 7;   // ar 0..31, ac 0..7
    const int ph2 = min(selh3[0], 3), pw2 = min(selw3[0], 3);
    int baseA[4];
#pragma unroll
    for (int t = 0; t < 4; ++t) {
        int mr = m0 + ar + 32 * t;
        int bq = mr / 9, p = mr - bq * 9;
        int pos = (ph2 + p / 3) * 6 + (pw2 + p % 3);
        baseA[t] = bq * 196 + min(2 * (pos / 6) + selh2[pos], 11) * 14
                            + min(2 * (pos % 6) + selw2[pos], 11);
    }
    auto gatherA = [&](int kt, int base) -> uint4 {
        int chunk = kt * 8 + ac;                     // 0..231
        if (chunk >= 225) return make_uint4(0u, 0u, 0u, 0u);
        int k3 = chunk / 25, c8 = chunk - k3 * 25;
        int srow = base + (k3 / 3) * 14 + (k3 - (k3 / 3) * 3);
        return *reinterpret_cast<const uint4*>(h1b + (size_t)srow * 200 + c8 * 8);
    };
    const uint4* Bg[4];
    uint4* As[4];
    uint4* Bs[4];
#pragma unroll
    for (int t = 0; t < 4; ++t) {
        Bg[t] = reinterpret_cast<const uint4*>(B + (size_t)(n0 + ar + 32 * t) * KP + ac * 8);
        As[t] = reinterpret_cast<uint4*>(&Asm[ar + 32 * t][ac * 8]);
        Bs[t] = reinterpret_cast<uint4*>(&Bsm[ar + 32 * t][ac * 8]);
    }
    uint4 ra[4], rb[4];
#pragma unroll
    for (int t = 0; t < 4; ++t) { ra[t] = gatherA(0, baseA[t]); rb[t] = Bg[t][0]; }

    const int r = lane & 15, ks = lane >> 4;
    for (int kt = 0; kt < NKT; ++kt) {
        __syncthreads();
#pragma unroll
        for (int t = 0; t < 4; ++t) { *As[t] = ra[t]; *Bs[t] = rb[t]; }
        __syncthreads();
        if (kt + 1 < NKT) {
#pragma unroll
            for (int t = 0; t < 4; ++t) {
                ra[t] = gatherA(kt + 1, baseA[t]);
                rb[t] = Bg[t][(kt + 1) * 8];
            }
        }
#pragma unroll
        for (int s = 0; s < 2; ++s) {
            bf16x8 a[4], bb[4];
#pragma unroll
            for (int mi = 0; mi < 4; ++mi)
                a[mi] = *reinterpret_cast<const bf16x8*>(&Asm[wm * 64 + mi * 16 + r][s * 32 + ks * 8]);
#pragma unroll
            for (int ni = 0; ni < 4; ++ni)
                bb[ni] = *reinterpret_cast<const bf16x8*>(&Bsm[wn * 64 + ni * 16 + r][s * 32 + ks * 8]);
#pragma unroll
            for (int mi = 0; mi < 4; ++mi)
#pragma unroll
                for (int ni = 0; ni < 4; ++ni)
                    acc[mi][ni] = __builtin_amdgcn_mfma_f32_16x16x32_bf16(a[mi], bb[ni], acc[mi][ni], 0, 0, 0);
        }
    }
    const int colb = n0 + wn * 64 + (lane & 15);
    const int rowb = m0 + wm * 64 + ((lane >> 4) << 2);
#pragma unroll
    for (int mi = 0; mi < 4; ++mi)
#pragma unroll
        for (int ni = 0; ni < 4; ++ni) {
            int oc = colb + ni * 16;
            if (oc < 400) {
                float bv = bias[oc];
#pragma unroll
                for (int rr = 0; rr < 4; ++rr) {
                    int row = rowb + mi * 16 + rr;
                    int bq = row / 9, pq = row - bq * 9;
                    P3[(size_t)bq * 3648 + pq * 400 + oc] = f2bf(fmaxf(acc[mi][ni][rr] + bv, 0.0f));
                }
            }
        }
}

// ---------- gemm_l3: split-K=2. z=0: kt 0..27 -> h3a (+bias); z=1: kt 28..56 -> h3b ----------
__global__ __launch_bounds__(256) void gemm_l3(
    const u16* __restrict__ A, const u16* __restrict__ B,
    const float* __restrict__ bias, float* __restrict__ h3a, float* __restrict__ h3b)
{
    const int KP = 3648;
    const int z = blockIdx.z;
    const int kt0 = z ? 28 : 0;
    const int NKT = z ? 29 : 28;
    const int m0 = blockIdx.x * 64, n0 = blockIdx.y * 64;
    const int tid = threadIdx.x;
    const int lane = tid & 63, wid = tid >> 6;
    const int wm = wid >> 1, wn = wid & 1;

    __shared__ u16 Asm[64][72];
    __shared__ u16 Bsm[64][72];

    f32x4 zero = {0.f, 0.f, 0.f, 0.f};
    f32x4 acc00 = zero, acc01 = zero, acc10 = zero, acc11 = zero;

    const int ar = tid >> 3, ac = tid & 7;
    auto gatherA = [&](int kt, int row) -> uint4 {   // zero-fill kk >= 3600
        int chunk = kt * 8 + ac;
        if (chunk >= 450) return make_uint4(0u, 0u, 0u, 0u);
        return *reinterpret_cast<const uint4*>(A + (size_t)row * KP + chunk * 8);
    };
    const uint4* Bg0 = reinterpret_cast<const uint4*>(B + (size_t)(n0 + ar) * KP + ac * 8);
    const uint4* Bg1 = reinterpret_cast<const uint4*>(B + (size_t)(n0 + ar + 32) * KP + ac * 8);
    uint4* As0 = reinterpret_cast<uint4*>(&Asm[ar][ac * 8]);
    uint4* As1 = reinterpret_cast<uint4*>(&Asm[ar + 32][ac * 8]);
    uint4* Bs0 = reinterpret_cast<uint4*>(&Bsm[ar][ac * 8]);
    uint4* Bs1 = reinterpret_cast<uint4*>(&Bsm[ar + 32][ac * 8]);

    uint4 ra0 = gatherA(kt0, m0 + ar), ra1 = gatherA(kt0, m0 + ar + 32);
    uint4 rb0 = Bg0[kt0 * 8], rb1 = Bg1[kt0 * 8];
    const int r = lane & 15, ks = lane >> 4;
    for (int kt = 0; kt < NKT; ++kt) {
        __syncthreads();
        *As0 = ra0; *As1 = ra1; *Bs0 = rb0; *Bs1 = rb1;
        __syncthreads();
        if (kt + 1 < NKT) {
            ra0 = gatherA(kt0 + kt + 1, m0 + ar); ra1 = gatherA(kt0 + kt + 1, m0 + ar + 32);
            rb0 = Bg0[(kt0 + kt + 1) * 8];        rb1 = Bg1[(kt0 + kt + 1) * 8];
        }
#pragma unroll
        for (int s = 0; s < 2; ++s) {
            bf16x8 a0 = *reinterpret_cast<const bf16x8*>(&Asm[wm * 32 + r][s * 32 + ks * 8]);
            bf16x8 a1 = *reinterpret_cast<const bf16x8*>(&Asm[wm * 32 + 16 + r][s * 32 + ks * 8]);
            bf16x8 b0 = *reinterpret_cast<const bf16x8*>(&Bsm[wn * 32 + r][s * 32 + ks * 8]);
            bf16x8 b1 = *reinterpret_cast<const bf16x8*>(&Bsm[wn * 32 + 16 + r][s * 32 + ks * 8]);
            acc00 = __builtin_amdgcn_mfma_f32_16x16x32_bf16(a0, b0, acc00, 0, 0, 0);
            acc01 = __builtin_amdgcn_mfma_f32_16x16x32_bf16(a0, b1, acc01, 0, 0, 0);
            acc10 = __builtin_amdgcn_mfma_f32_16x16x32_bf16(a1, b0, acc10, 0, 0, 0);
            acc11 = __builtin_amdgcn_mfma_f32_16x16x32_bf16(a1, b1, acc11, 0, 0, 0);
        }
    }
    const int colb = n0 + wn * 32 + (lane & 15);
    const int rowb = m0 + wm * 32 + ((lane >> 4) << 2);
    float* dst = z ? h3b : h3a;
#define L3STORE(ACC, MR, NR) { \
    int oc = colb + (NR) * 16; \
    if (oc < 800) { float bv = z ? 0.0f : bias[oc]; \
        _Pragma("unroll") \
        for (int rr = 0; rr < 4; ++rr) { \
            int row = rowb + (MR) * 16 + rr; \
            dst[(size_t)row * 800 + oc] = ACC[rr] + bv; \
        } } }
    L3STORE(acc00, 0, 0) L3STORE(acc01, 0, 1) L3STORE(acc10, 1, 0) L3STORE(acc11, 1, 1)
#undef L3STORE
}

// ---------- FC: relu(h3a+h3b) @ fc_w^T + fc_b ----------
__global__ __launch_bounds__(256) void fc_kernel(
    const float* __restrict__ h3a, const float* __restrict__ h3b,
    const float* __restrict__ fcw, const float* __restrict__ fcb,
    float* __restrict__ out)
{
    const int idx = blockIdx.x * 256 + threadIdx.x;
    if (idx >= 1024 * 10) return;
    const int b = idx / 10, o = idx % 10;
    float acc = fcb[o];
    const float4* hp0 = reinterpret_cast<const float4*>(h3a + b * 800);
    const float4* hp1 = reinterpret_cast<const float4*>(h3b + b * 800);
    const float4* wp  = reinterpret_cast<const float4*>(fcw + o * 800);
    for (int k = 0; k < 200; ++k) {
        float4 p0 = hp0[k], p1 = hp1[k], w = wp[k];
        acc = fmaf(fmaxf(p0.x + p1.x, 0.0f), w.x, acc);
        acc = fmaf(fmaxf(p0.y + p1.y, 0.0f), w.y, acc);
        acc = fmaf(fmaxf(p0.z + p1.z, 0.0f), w.z, acc);
        acc = fmaf(fmaxf(p0.w + p1.w, 0.0f), w.w, acc);
    }
    out[idx] = acc;
}

extern "C" void kernel_launch(void* const* d_in, const int* in_sizes, int n_in,
                              void* d_out, int out_size, void* d_ws, size_t ws_size,
                              hipStream_t stream) {
    const float* x     = (const float*)d_in[0];
    const float* W1    = (const float*)d_in[1];
    const float* b1    = (const float*)d_in[2];
    const float* W2    = (const float*)d_in[3];
    const float* b2    = (const float*)d_in[4];
    const float* W3    = (const float*)d_in[5];
    const float* b3    = (const float*)d_in[6];
    const float* fc_w  = (const float*)d_in[7];
    const float* fc_b  = (const float*)d_in[8];
    const int*   selh1 = (const int*)d_in[9];
    const int*   selw1 = (const int*)d_in[10];
    const int*   selh2 = (const int*)d_in[11];
    const int*   selw2 = (const int*)d_in[12];
    const int*   selh3 = (const int*)d_in[13];
    const int*   selw3 = (const int*)d_in[14];
    const float* mask1 = (const float*)d_in[15];

    char* wsb = (char*)d_ws;
    u16*   h1b = (u16*)(wsb + H1B_OFF);
    u16*   W2b = (u16*)(wsb + W2B_OFF);
    u16*   P3  = (u16*)(wsb + P3_OFF);
    u16*   W3b = (u16*)(wsb + W3B_OFF);
    float* h3a = (float*)(wsb + H3A_OFF);
    float* h3b = (float*)(wsb + H3B_OFF);
    float* W1t = (float*)(wsb + W1T_OFF);
    float* out = (float*)d_out;

    wprep<<<15648, 256, 0, stream>>>(W1, W2, W3, W1t, W2b, W3b);
    l1_kernel<<<dim3(196, 32), 256, 0, stream>>>(x, W1t, b1, selh1, selw1, mask1, h1b);
    gemm_l2<<<dim3(72, 4), 256, 0, stream>>>(h1b, W2b, b2, selh2, selw2, selh3, selw3, P3);
    gemm_l3<<<dim3(16, 13, 2), 256, 0, stream>>>(P3, W3b, b3, h3a, h3b);
    fc_kernel<<<40, 256, 0, stream>>>(h3a, h3b, fc_w, fc_b, out);
}

// Round 16
// 283.143 us; speedup vs baseline: 1.0543x; 1.0543x over previous
//
#include <hip/hip_runtime.h>

// MyLeNetMatStochBU, B=1024. fp32-VALU l1 (reg-pipelined) + bf16-MFMA l2 (128x64)
// + l3 (64^2, split-K=2).
//
// Structural facts (from reference construction):
//  - mask3 = single position; mask2 = exactly 9 active positions (3x3 block).
//  - mask1 = union of l2's read windows -> masked l1 positions never read.
//  - l3's im2col of h2 == l2's output re-indexed -> gemm_l2 writes P3 directly.
//  - l1 fp32 VALU (MFMA-l1 2.4x slower, r8).
//  - r14: l2 128x128 tile = 288 blocks = 1.1/CU -> 11% occupancy, barrier-bound
//    (MfmaUtil 7.6%). This round: BN 128->64, grid 576 = 2.25 blocks/CU.
//
// ws layout (BYTE offsets, 16B-aligned):
//   h1b : bf16 (1024,14,14,200) NHWC @ 0            80,281,600 B
//   W2b : bf16 [512][1856]           @  80,281,600   1,900,544 B
//   P3  : bf16 [1024][3648]          @  82,182,144   7,471,104 B
//   W3b : bf16 [832][3648]           @  89,653,248   6,070,272 B
//   h3a : f32  [1024][800]           @  95,723,520   3,276,800 B
//   h3b : f32  [1024][800]           @  99,000,320   3,276,800 B
//   W1t : f32  [80][256] K-major     @ 102,277,120      81,920 B
// total ~102.4 MB.

#define H1B_OFF 0ULL
#define W2B_OFF 80281600ULL
#define P3_OFF  82182144ULL
#define W3B_OFF 89653248ULL
#define H3A_OFF 95723520ULL
#define H3B_OFF 99000320ULL
#define W1T_OFF 102277120ULL

typedef unsigned short u16;
typedef short bf16x8 __attribute__((ext_vector_type(8)));
typedef float f32x4 __attribute__((ext_vector_type(4)));

__device__ __forceinline__ u16 f2bf(float f) {
    union { float f; unsigned int u; } v; v.f = f;
    unsigned int u = v.u + 0x7FFFu + ((v.u >> 16) & 1u);   // RNE
    return (u16)(u >> 16);
}

// ---------- wprep ----------
__global__ __launch_bounds__(256) void wprep(
    const float* __restrict__ W1, const float* __restrict__ W2, const float* __restrict__ W3,
    float* __restrict__ W1t, u16* __restrict__ W2b, u16* __restrict__ W3b)
{
    int idx = blockIdx.x * 256 + threadIdx.x;
    if (idx < 20480) {                               // W1t [80 kk][256 ocp]
        int kk = idx / 256, oc = idx % 256;
        float v = 0.0f;
        if (oc < 200 && kk < 75) v = W1[oc * 75 + kk];
        W1t[idx] = v;
    } else if (idx < 20480 + 950272) {               // W2b [512][1856], kk=k3*200+c
        int j = idx - 20480;
        int oc = j / 1856, kk = j % 1856;
        float v = 0.0f;
        if (oc < 400 && kk < 1800) {
            int k3 = kk / 200, c = kk % 200;
            v = W2[oc * 1800 + c * 9 + k3];
        }
        W2b[j] = f2bf(v);
    } else if (idx < 20480 + 950272 + 3035136) {     // W3b [832][3648], kk=k3*400+c
        int j = idx - 20480 - 950272;
        int oc = j / 3648, kk = j % 3648;
        float v = 0.0f;
        if (oc < 800 && kk < 3600) {
            int k3 = kk / 400, c = kk % 400;
            v = W3[oc * 3600 + c * 9 + k3];
        }
        W3b[j] = f2bf(v);
    }
}

// ---------- L1: fp32 FMA, 4oc x 8u tile, 32 batches/block, weight reg-prefetch ----------
__global__ __launch_bounds__(256) void l1_kernel(
    const float* __restrict__ x, const float* __restrict__ W1t, const float* __restrict__ b1,
    const int* __restrict__ selh, const int* __restrict__ selw, const float* __restrict__ mask,
    u16* __restrict__ h1b)
{
    const int pos = blockIdx.x;              // 0..195
    const float m = mask[pos];
    if (m == 0.0f) return;
    const int i = pos / 14, j = pos % 14;
    const int b0 = blockIdx.y * 32;
    const int tid = threadIdx.x;
    const int ph = min(i * 2 + selh[pos], 27);
    const int pw = min(j * 2 + selw[pos], 27);

    __shared__ __align__(16) float patch[32 * 80];   // [u][kk], kk=c*25+d pad 80
    for (int e = tid; e < 2560; e += 256) {
        int u = e / 80, kk = e % 80;
        float v = 0.0f;
        if (kk < 75) {
            int c = kk / 25, d = kk % 25;
            v = x[((size_t)(b0 + u) * 3 + c) * 1024 + (ph + d / 5) * 32 + (pw + d % 5)];
        }
        patch[e] = v;
    }
    __syncthreads();

    const int g = tid & 63;                  // oc = g*4 .. g*4+3 (padded weights)
    const int us = tid >> 6;                 // u = us*8 .. us*8+7
    const float4* w4 = reinterpret_cast<const float4*>(W1t);     // [80][64]
    const float4* p4 = reinterpret_cast<const float4*>(patch);   // [32][20]

    float4 acc[8];
#pragma unroll
    for (int uu = 0; uu < 8; ++uu) acc[uu] = make_float4(0.f, 0.f, 0.f, 0.f);

    float4 wc[4];
#pragma unroll
    for (int t = 0; t < 4; ++t) wc[t] = w4[t * 64 + g];

    for (int q = 0; q < 20; ++q) {
        // prefetch q+1 weights while FMAs below consume wc (hides ~200cy latency)
        int qq = min(q + 1, 19);
        float4 wn[4];
#pragma unroll
        for (int t = 0; t < 4; ++t) wn[t] = w4[(qq * 4 + t) * 64 + g];

#pragma unroll
        for (int uu = 0; uu < 8; ++uu) {
            float4 p = p4[(us * 8 + uu) * 20 + q];   // wave-uniform broadcast
            acc[uu].x = fmaf(wc[0].x, p.x, acc[uu].x);
            acc[uu].y = fmaf(wc[0].y, p.x, acc[uu].y);
            acc[uu].z = fmaf(wc[0].z, p.x, acc[uu].z);
            acc[uu].w = fmaf(wc[0].w, p.x, acc[uu].w);
            acc[uu].x = fmaf(wc[1].x, p.y, acc[uu].x);
            acc[uu].y = fmaf(wc[1].y, p.y, acc[uu].y);
            acc[uu].z = fmaf(wc[1].z, p.y, acc[uu].z);
            acc[uu].w = fmaf(wc[1].w, p.y, acc[uu].w);
            acc[uu].x = fmaf(wc[2].x, p.z, acc[uu].x);
            acc[uu].y = fmaf(wc[2].y, p.z, acc[uu].y);
            acc[uu].z = fmaf(wc[2].z, p.z, acc[uu].z);
            acc[uu].w = fmaf(wc[2].w, p.z, acc[uu].w);
            acc[uu].x = fmaf(wc[3].x, p.w, acc[uu].x);
            acc[uu].y = fmaf(wc[3].y, p.w, acc[uu].y);
            acc[uu].z = fmaf(wc[3].z, p.w, acc[uu].z);
            acc[uu].w = fmaf(wc[3].w, p.w, acc[uu].w);
        }
#pragma unroll
        for (int t = 0; t < 4; ++t) wc[t] = wn[t];
    }

    if (g < 50) {                            // oc = g*4..g*4+3 all < 200
        float4 bv = reinterpret_cast<const float4*>(b1)[g];
#pragma unroll
        for (int uu = 0; uu < 8; ++uu) {
            int b = b0 + us * 8 + uu;
            ushort4 o;
            o.x = f2bf(fmaxf((acc[uu].x + bv.x) * m, 0.0f));
            o.y = f2bf(fmaxf((acc[uu].y + bv.y) * m, 0.0f));
            o.z = f2bf(fmaxf((acc[uu].z + bv.z) * m, 0.0f));
            o.w = f2bf(fmaxf((acc[uu].w + bv.w) * m, 0.0f));
            *reinterpret_cast<ushort4*>(&h1b[((size_t)b * 196 + pos) * 200 + g * 4]) = o;
        }
    }
}

// ---------- gemm_l2: 128x64 tile, BK=64, fused im2col A-gather -> P3 ----------
// M=9216 (b*9+pidx), K=1800 pad 1856, N=448 pad 512. Grid (72,8)=576 blocks.
// 4 waves as 2x2: wave = 64 rows x 32 cols = acc[4][2] 16x16 frags.
__global__ __launch_bounds__(256) void gemm_l2(
    const u16* __restrict__ h1b, const u16* __restrict__ B, const float* __restrict__ bias,
    const int* __restrict__ selh2, const int* __restrict__ selw2,
    const int* __restrict__ selh3, const int* __restrict__ selw3,
    u16* __restrict__ P3)
{
    const int KP = 1856, NKT = 29;
    const int m0 = blockIdx.x * 128, n0 = blockIdx.y * 64;
    const int tid = threadIdx.x;
    const int lane = tid & 63, wid = tid >> 6;
    const int wm = wid >> 1, wn = wid & 1;

    __shared__ u16 Asm[128][72];
    __shared__ u16 Bsm[64][72];

    f32x4 acc[4][2];
#pragma unroll
    for (int mi = 0; mi < 4; ++mi)
#pragma unroll
        for (int ni = 0; ni < 2; ++ni) {
            f32x4 z = {0.f, 0.f, 0.f, 0.f};
            acc[mi][ni] = z;
        }

    const int ar = tid >> 3, ac = tid & 7;   // ar 0..31, ac 0..7
    const int ph2 = min(selh3[0], 3), pw2 = min(selw3[0], 3);
    int baseA[4];
#pragma unroll
    for (int t = 0; t < 4; ++t) {
        int mr = m0 + ar + 32 * t;
        int bq = mr / 9, p = mr - bq * 9;
        int pos = (ph2 + p / 3) * 6 + (pw2 + p % 3);
        baseA[t] = bq * 196 + min(2 * (pos / 6) + selh2[pos], 11) * 14
                            + min(2 * (pos % 6) + selw2[pos], 11);
    }
    auto gatherA = [&](int kt, int base) -> uint4 {
        int chunk = kt * 8 + ac;                     // 0..231
        if (chunk >= 225) return make_uint4(0u, 0u, 0u, 0u);
        int k3 = chunk / 25, c8 = chunk - k3 * 25;
        int srow = base + (k3 / 3) * 14 + (k3 - (k3 / 3) * 3);
        return *reinterpret_cast<const uint4*>(h1b + (size_t)srow * 200 + c8 * 8);
    };
    const uint4* Bg[2];
    uint4* As[4];
    uint4* Bs[2];
#pragma unroll
    for (int t = 0; t < 4; ++t)
        As[t] = reinterpret_cast<uint4*>(&Asm[ar + 32 * t][ac * 8]);
#pragma unroll
    for (int t = 0; t < 2; ++t) {
        Bg[t] = reinterpret_cast<const uint4*>(B + (size_t)(n0 + ar + 32 * t) * KP + ac * 8);
        Bs[t] = reinterpret_cast<uint4*>(&Bsm[ar + 32 * t][ac * 8]);
    }
    uint4 ra[4], rb[2];
#pragma unroll
    for (int t = 0; t < 4; ++t) ra[t] = gatherA(0, baseA[t]);
#pragma unroll
    for (int t = 0; t < 2; ++t) rb[t] = Bg[t][0];

    const int r = lane & 15, ks = lane >> 4;
    for (int kt = 0; kt < NKT; ++kt) {
        __syncthreads();
#pragma unroll
        for (int t = 0; t < 4; ++t) *As[t] = ra[t];
#pragma unroll
        for (int t = 0; t < 2; ++t) *Bs[t] = rb[t];
        __syncthreads();
        if (kt + 1 < NKT) {
#pragma unroll
            for (int t = 0; t < 4; ++t) ra[t] = gatherA(kt + 1, baseA[t]);
#pragma unroll
            for (int t = 0; t < 2; ++t) rb[t] = Bg[t][(kt + 1) * 8];
        }
#pragma unroll
        for (int s = 0; s < 2; ++s) {
            bf16x8 a[4], bb[2];
#pragma unroll
            for (int mi = 0; mi < 4; ++mi)
                a[mi] = *reinterpret_cast<const bf16x8*>(&Asm[wm * 64 + mi * 16 + r][s * 32 + ks * 8]);
#pragma unroll
            for (int ni = 0; ni < 2; ++ni)
                bb[ni] = *reinterpret_cast<const bf16x8*>(&Bsm[wn * 32 + ni * 16 + r][s * 32 + ks * 8]);
#pragma unroll
            for (int mi = 0; mi < 4; ++mi)
#pragma unroll
                for (int ni = 0; ni < 2; ++ni)
                    acc[mi][ni] = __builtin_amdgcn_mfma_f32_16x16x32_bf16(a[mi], bb[ni], acc[mi][ni], 0, 0, 0);
        }
    }
    const int colb = n0 + wn * 32 + (lane & 15);
    const int rowb = m0 + wm * 64 + ((lane >> 4) << 2);
#pragma unroll
    for (int mi = 0; mi < 4; ++mi)
#pragma unroll
        for (int ni = 0; ni < 2; ++ni) {
            int oc = colb + ni * 16;
            if (oc < 400) {
                float bv = bias[oc];
#pragma unroll
                for (int rr = 0; rr < 4; ++rr) {
                    int row = rowb + mi * 16 + rr;
                    int bq = row / 9, pq = row - bq * 9;
                    P3[(size_t)bq * 3648 + pq * 400 + oc] = f2bf(fmaxf(acc[mi][ni][rr] + bv, 0.0f));
                }
            }
        }
}

// ---------- gemm_l3: split-K=2. z=0: kt 0..27 -> h3a (+bias); z=1: kt 28..56 -> h3b ----------
__global__ __launch_bounds__(256) void gemm_l3(
    const u16* __restrict__ A, const u16* __restrict__ B,
    const float* __restrict__ bias, float* __restrict__ h3a, float* __restrict__ h3b)
{
    const int KP = 3648;
    const int z = blockIdx.z;
    const int kt0 = z ? 28 : 0;
    const int NKT = z ? 29 : 28;
    const int m0 = blockIdx.x * 64, n0 = blockIdx.y * 64;
    const int tid = threadIdx.x;
    const int lane = tid & 63, wid = tid >> 6;
    const int wm = wid >> 1, wn = wid & 1;

    __shared__ u16 Asm[64][72];
    __shared__ u16 Bsm[64][72];

    f32x4 zero = {0.f, 0.f, 0.f, 0.f};
    f32x4 acc00 = zero, acc01 = zero, acc10 = zero, acc11 = zero;

    const int ar = tid >> 3, ac = tid & 7;
    auto gatherA = [&](int kt, int row) -> uint4 {   // zero-fill kk >= 3600
        int chunk = kt * 8 + ac;
        if (chunk >= 450) return make_uint4(0u, 0u, 0u, 0u);
        return *reinterpret_cast<const uint4*>(A + (size_t)row * KP + chunk * 8);
    };
    const uint4* Bg0 = reinterpret_cast<const uint4*>(B + (size_t)(n0 + ar) * KP + ac * 8);
    const uint4* Bg1 = reinterpret_cast<const uint4*>(B + (size_t)(n0 + ar + 32) * KP + ac * 8);
    uint4* As0 = reinterpret_cast<uint4*>(&Asm[ar][ac * 8]);
    uint4* As1 = reinterpret_cast<uint4*>(&Asm[ar + 32][ac * 8]);
    uint4* Bs0 = reinterpret_cast<uint4*>(&Bsm[ar][ac * 8]);
    uint4* Bs1 = reinterpret_cast<uint4*>(&Bsm[ar + 32][ac * 8]);

    uint4 ra0 = gatherA(kt0, m0 + ar), ra1 = gatherA(kt0, m0 + ar + 32);
    uint4 rb0 = Bg0[kt0 * 8], rb1 = Bg1[kt0 * 8];
    const int r = lane & 15, ks = lane >> 4;
    for (int kt = 0; kt < NKT; ++kt) {
        __syncthreads();
        *As0 = ra0; *As1 = ra1; *Bs0 = rb0; *Bs1 = rb1;
        __syncthreads();
        if (kt + 1 < NKT) {
            ra0 = gatherA(kt0 + kt + 1, m0 + ar); ra1 = gatherA(kt0 + kt + 1, m0 + ar + 32);
            rb0 = Bg0[(kt0 + kt + 1) * 8];        rb1 = Bg1[(kt0 + kt + 1) * 8];
        }
#pragma unroll
        for (int s = 0; s < 2; ++s) {
            bf16x8 a0 = *reinterpret_cast<const bf16x8*>(&Asm[wm * 32 + r][s * 32 + ks * 8]);
            bf16x8 a1 = *reinterpret_cast<const bf16x8*>(&Asm[wm * 32 + 16 + r][s * 32 + ks * 8]);
            bf16x8 b0 = *reinterpret_cast<const bf16x8*>(&Bsm[wn * 32 + r][s * 32 + ks * 8]);
            bf16x8 b1 = *reinterpret_cast<const bf16x8*>(&Bsm[wn * 32 + 16 + r][s * 32 + ks * 8]);
            acc00 = __builtin_amdgcn_mfma_f32_16x16x32_bf16(a0, b0, acc00, 0, 0, 0);
            acc01 = __builtin_amdgcn_mfma_f32_16x16x32_bf16(a0, b1, acc01, 0, 0, 0);
            acc10 = __builtin_amdgcn_mfma_f32_16x16x32_bf16(a1, b0, acc10, 0, 0, 0);
            acc11 = __builtin_amdgcn_mfma_f32_16x16x32_bf16(a1, b1, acc11, 0, 0, 0);
        }
    }
    const int colb = n0 + wn * 32 + (lane & 15);
    const int rowb = m0 + wm * 32 + ((lane >> 4) << 2);
    float* dst = z ? h3b : h3a;
#define L3STORE(ACC, MR, NR) { \
    int oc = colb + (NR) * 16; \
    if (oc < 800) { float bv = z ? 0.0f : bias[oc]; \
        _Pragma("unroll") \
        for (int rr = 0; rr < 4; ++rr) { \
            int row = rowb + (MR) * 16 + rr; \
            dst[(size_t)row * 800 + oc] = ACC[rr] + bv; \
        } } }
    L3STORE(acc00, 0, 0) L3STORE(acc01, 0, 1) L3STORE(acc10, 1, 0) L3STORE(acc11, 1, 1)
#undef L3STORE
}

// ---------- FC: relu(h3a+h3b) @ fc_w^T + fc_b ----------
__global__ __launch_bounds__(256) void fc_kernel(
    const float* __restrict__ h3a, const float* __restrict__ h3b,
    const float* __restrict__ fcw, const float* __restrict__ fcb,
    float* __restrict__ out)
{
    const int idx = blockIdx.x * 256 + threadIdx.x;
    if (idx >= 1024 * 10) return;
    const int b = idx / 10, o = idx % 10;
    float acc = fcb[o];
    const float4* hp0 = reinterpret_cast<const float4*>(h3a + b * 800);
    const float4* hp1 = reinterpret_cast<const float4*>(h3b + b * 800);
    const float4* wp  = reinterpret_cast<const float4*>(fcw + o * 800);
    for (int k = 0; k < 200; ++k) {
        float4 p0 = hp0[k], p1 = hp1[k], w = wp[k];
        acc = fmaf(fmaxf(p0.x + p1.x, 0.0f), w.x, acc);
        acc = fmaf(fmaxf(p0.y + p1.y, 0.0f), w.y, acc);
        acc = fmaf(fmaxf(p0.z + p1.z, 0.0f), w.z, acc);
        acc = fmaf(fmaxf(p0.w + p1.w, 0.0f), w.w, acc);
    }
    out[idx] = acc;
}

extern "C" void kernel_launch(void* const* d_in, const int* in_sizes, int n_in,
                              void* d_out, int out_size, void* d_ws, size_t ws_size,
                              hipStream_t stream) {
    const float* x     = (const float*)d_in[0];
    const float* W1    = (const float*)d_in[1];
    const float* b1    = (const float*)d_in[2];
    const float* W2    = (const float*)d_in[3];
    const float* b2    = (const float*)d_in[4];
    const float* W3    = (const float*)d_in[5];
    const float* b3    = (const float*)d_in[6];
    const float* fc_w  = (const float*)d_in[7];
    const float* fc_b  = (const float*)d_in[8];
    const int*   selh1 = (const int*)d_in[9];
    const int*   selw1 = (const int*)d_in[10];
    const int*   selh2 = (const int*)d_in[11];
    const int*   selw2 = (const int*)d_in[12];
    const int*   selh3 = (const int*)d_in[13];
    const int*   selw3 = (const int*)d_in[14];
    const float* mask1 = (const float*)d_in[15];

    char* wsb = (char*)d_ws;
    u16*   h1b = (u16*)(wsb + H1B_OFF);
    u16*   W2b = (u16*)(wsb + W2B_OFF);
    u16*   P3  = (u16*)(wsb + P3_OFF);
    u16*   W3b = (u16*)(wsb + W3B_OFF);
    float* h3a = (float*)(wsb + H3A_OFF);
    float* h3b = (float*)(wsb + H3B_OFF);
    float* W1t = (float*)(wsb + W1T_OFF);
    float* out = (float*)d_out;

    wprep<<<15648, 256, 0, stream>>>(W1, W2, W3, W1t, W2b, W3b);
    l1_kernel<<<dim3(196, 32), 256, 0, stream>>>(x, W1t, b1, selh1, selw1, mask1, h1b);
    gemm_l2<<<dim3(72, 8), 256, 0, stream>>>(h1b, W2b, b2, selh2, selw2, selh3, selw3, P3);
    gemm_l3<<<dim3(16, 13, 2), 256, 0, stream>>>(P3, W3b, b3, h3a, h3b);
    fc_kernel<<<40, 256, 0, stream>>>(h3a, h3b, fc_w, fc_b, out);
}